// Round 12
// baseline (115.602 us; speedup 1.0000x reference)
//
#include <hip/hip_runtime.h>
#include <math.h>

// Chamfer distance, N=M=16384, D=3, fp32 — R14: no cross-lane ops in loop.
// R13 audit: occupancy changes (2.6 -> 4+ waves/SIMD) never moved the
// ~35us tile plateau, so the binding constraint is the per-iter chain:
// ds_read -> MFMA -> 31-deep min tree -> ds_bpermute (shfl_xor, ~120cy)
// -> dependent store. R14 removes the shfl: each lane (cl,half) stores its
// OWN half-col partial (min over its 32 C values = 32 of the wave's 64 i)
// to colW[strip*8 + w*2 + half][N]. Inner loop: 1 ds_read, 2 MFMA,
// 63 v_min, 1 plain store. Zero bpermutes, zero exec masks, zero barriers.
// chamfer_sum absorbs the cost: col path reduces 512 rows (32MB, ~+3us).
// MFMA slot packing (bit-clean R9-R13): k0-8 2-way-split cross terms,
// k9-11 |a|^2 3-way (x1 on B), k12-14 |b|^2 3-way (x1 on A).

typedef short s16x8 __attribute__((ext_vector_type(8)));
typedef float f32x16 __attribute__((ext_vector_type(16)));

constexpr int N       = 16384;
constexpr int THREADS = 256;           // 4 waves
constexpr int ISTRIP  = 256;           // i's per block (4 waves x 2 tiles x 32)
constexpr int NSTRIPS = N / ISTRIP;    // 64
constexpr int JCHUNK  = 1024;          // j's per block
constexpr int NCHUNKS = N / JCHUNK;    // 16
constexpr int NJT     = JCHUNK / 32;   // 32 j-tiles
constexpr int NCROWS  = NSTRIPS * 8;   // 512 col-partial rows (per half)
constexpr float INF_F = 3.402823466e+38f;
constexpr short ONE_BF = (short)0x3F80;  // bf16(1.0)

static __device__ __forceinline__ short bf_hi(float x) {  // RN bf16 bits
  unsigned u = __float_as_uint(x);
  unsigned r = (u + 0x7fffu + ((u >> 16) & 1u)) >> 16;
  return (short)r;
}
static __device__ __forceinline__ float bf_val(short h) {
  return __uint_as_float(((unsigned)(unsigned short)h) << 16);
}

__global__ __launch_bounds__(THREADS, 4) void chamfer_mfma(
    const float* __restrict__ p1, const float* __restrict__ p2,
    float* __restrict__ rowPart, float* __restrict__ colW,
    float* __restrict__ out) {
  // 32KB: bfrag [NJT][64] s16x8 during the loop; rmt [4][2][32][32] f32
  // (row-min transpose) aliases it after the post-loop barrier.
  __shared__ __align__(16) float smem[8192];
  s16x8* const bfrag = (s16x8*)smem;
  float* const rmt   = smem;

  const int tid  = threadIdx.x;
  const int l    = tid & 63;
  const int w    = tid >> 6;
  const int cl   = l & 31;   // col-in-tile (B,C) / row-in-tile (A)
  const int half = l >> 5;   // k-octet owner / C row-quadrant owner
  const int bid  = blockIdx.x;
  const int strip = bid & (NSTRIPS - 1);
  const int chunk = bid >> 6;            // NSTRIPS == 64
  const int i0 = strip * ISTRIP;
  const int j0 = chunk * JCHUNK;

  if (bid == 0 && tid == 0) *out = 0.0f;  // ordered before sum's atomics

  // ---- stage B fragments: 4 points per thread ----
  for (int jl = tid; jl < JCHUNK; jl += THREADS) {
    const float* bp = p2 + (size_t)(j0 + jl) * 3;
    const float ox = bp[0], oy = bp[1], oz = bp[2];
    const float sb = fmaf(ox, ox, fmaf(oy, oy, oz * oz));
    const float bx = -2.0f * ox, by = -2.0f * oy, bz = -2.0f * oz;
    const short bhx = bf_hi(bx), blx = bf_hi(bx - bf_val(bhx));
    const short bhy = bf_hi(by), bly = bf_hi(by - bf_val(bhy));
    const short bhz = bf_hi(bz), blz = bf_hi(bz - bf_val(bhz));
    const short sbh = bf_hi(sb);
    const float r1 = sb - bf_val(sbh);
    const short sbm = bf_hi(r1);
    const short sbl = bf_hi(r1 - bf_val(sbm));
    const int jt = jl >> 5, c = jl & 31;
    bfrag[jt * 64 + c]      = (s16x8){bhx, blx, bhx, bhy, bly, bhy, bhz, blz};
    bfrag[jt * 64 + 32 + c] = (s16x8){bhz, ONE_BF, ONE_BF, ONE_BF,
                                      sbh, sbm, sbl, 0};
  }

  // ---- A fragments: 2 row-tiles (64 i's) per wave, in registers ----
#define ABUILD(t, AF)                                                        \
  s16x8 AF;                                                                  \
  {                                                                          \
    const float* ap = p1 + (size_t)(i0 + w * 64 + (t)*32 + cl) * 3;          \
    const float x = ap[0], y = ap[1], z = ap[2];                             \
    const float sa = fmaf(x, x, fmaf(y, y, z * z));                          \
    const short ahx = bf_hi(x), alx = bf_hi(x - bf_val(ahx));                \
    const short ahy = bf_hi(y), aly = bf_hi(y - bf_val(ahy));                \
    const short ahz = bf_hi(z), alz = bf_hi(z - bf_val(ahz));                \
    const short sah = bf_hi(sa);                                             \
    const float q1 = sa - bf_val(sah);                                       \
    const short sam = bf_hi(q1);                                             \
    const short sal = bf_hi(q1 - bf_val(sam));                               \
    AF = half ? (s16x8){alz, sah, sam, sal, ONE_BF, ONE_BF, ONE_BF, 0}       \
              : (s16x8){ahx, ahx, alx, ahy, ahy, aly, ahz, ahz};             \
  }
  ABUILD(0, A0) ABUILD(1, A1)
#undef ABUILD

  f32x16 RAa, RAb, zero16;
#pragma unroll
  for (int r = 0; r < 16; ++r) { RAa[r] = INF_F; RAb[r] = INF_F; zero16[r] = 0.0f; }

  __syncthreads();

  // jt-loop (rolled, unroll 2). Per iter: 1 ds_read_b128, 2 MFMA, 32 RA-min,
  // 16+15 tree-min over this lane's own 32 C values (rows {quad(half)} x
  // {tile0,tile1} = 32 of the wave's 64 i's), 1 plain coalesced store.
  float* const cwr = colW + (size_t)(strip * 8 + w * 2 + half) * N + j0 + cl;
#pragma unroll 2
  for (int jt = 0; jt < NJT; ++jt) {
    const s16x8 bf = bfrag[jt * 64 + l];
    const f32x16 C0 =
        __builtin_amdgcn_mfma_f32_32x32x16_bf16(A0, bf, zero16, 0, 0, 0);
    const f32x16 C1 =
        __builtin_amdgcn_mfma_f32_32x32x16_bf16(A1, bf, zero16, 0, 0, 0);
    RAa = __builtin_elementwise_min(RAa, C0);
    RAb = __builtin_elementwise_min(RAb, C1);
    const f32x16 t = __builtin_elementwise_min(C0, C1);
    const float u0 = fminf(fminf(t[0], t[1]), fminf(t[2], t[3]));
    const float u1 = fminf(fminf(t[4], t[5]), fminf(t[6], t[7]));
    const float u2 = fminf(fminf(t[8], t[9]), fminf(t[10], t[11]));
    const float u3 = fminf(fminf(t[12], t[13]), fminf(t[14], t[15]));
    cwr[jt * 32] = fminf(fminf(u0, u1), fminf(u2, u3));
  }

  __syncthreads();  // all bfrag reads done -> rmt may alias it

  // ---- row-min finish via LDS transpose (40 DS ops, no bpermute storm) ----
  {
    float* ra = &rmt[((w * 2 + 0) * 32 + cl) * 32 + half * 16];
    *(float4*)(ra + 0)  = make_float4(RAa[0], RAa[1], RAa[2], RAa[3]);
    *(float4*)(ra + 4)  = make_float4(RAa[4], RAa[5], RAa[6], RAa[7]);
    *(float4*)(ra + 8)  = make_float4(RAa[8], RAa[9], RAa[10], RAa[11]);
    *(float4*)(ra + 12) = make_float4(RAa[12], RAa[13], RAa[14], RAa[15]);
    float* rb = &rmt[((w * 2 + 1) * 32 + cl) * 32 + half * 16];
    *(float4*)(rb + 0)  = make_float4(RAb[0], RAb[1], RAb[2], RAb[3]);
    *(float4*)(rb + 4)  = make_float4(RAb[4], RAb[5], RAb[6], RAb[7]);
    *(float4*)(rb + 8)  = make_float4(RAb[8], RAb[9], RAb[10], RAb[11]);
    *(float4*)(rb + 12) = make_float4(RAb[12], RAb[13], RAb[14], RAb[15]);
  }
  {
    const int tl = l >> 5;
    const int s  = l & 31;
    const float* rp = &rmt[((w * 2 + tl) * 32) * 32 + s];
    float m = rp[0];
#pragma unroll
    for (int k = 1; k < 32; ++k) m = fminf(m, rp[k * 32]);
    const int r = s & 15, hh = s >> 4;
    const int row = (r & 3) + 8 * (r >> 2) + 4 * hh;
    rowPart[(size_t)chunk * N + i0 + w * 64 + tl * 32 + row] = m;
  }
}

// One thread per point (2*16384): min over partials (d^2 complete — norms
// were inside the MFMA), sqrt, block-sum, one atomicAdd into out[0].
__global__ __launch_bounds__(THREADS) void chamfer_sum(
    const float* __restrict__ rowPart, const float* __restrict__ colW,
    float* __restrict__ out) {
  const int p = blockIdx.x * THREADS + threadIdx.x;  // 0..32767
  float m0 = INF_F, m1 = INF_F, m2 = INF_F, m3 = INF_F;
  float m4 = INF_F, m5 = INF_F, m6 = INF_F, m7 = INF_F;
  if (p < N) {
    const float* rp = rowPart + p;
#pragma unroll
    for (int c = 0; c < NCHUNKS; c += 4) {
      m0 = fminf(m0, rp[(size_t)(c + 0) * N]);
      m1 = fminf(m1, rp[(size_t)(c + 1) * N]);
      m2 = fminf(m2, rp[(size_t)(c + 2) * N]);
      m3 = fminf(m3, rp[(size_t)(c + 3) * N]);
    }
  } else {
    const float* cp = colW + (p - N);
    for (int s = 0; s < NCROWS; s += 8) {
      m0 = fminf(m0, cp[(size_t)(s + 0) * N]);
      m1 = fminf(m1, cp[(size_t)(s + 1) * N]);
      m2 = fminf(m2, cp[(size_t)(s + 2) * N]);
      m3 = fminf(m3, cp[(size_t)(s + 3) * N]);
      m4 = fminf(m4, cp[(size_t)(s + 4) * N]);
      m5 = fminf(m5, cp[(size_t)(s + 5) * N]);
      m6 = fminf(m6, cp[(size_t)(s + 6) * N]);
      m7 = fminf(m7, cp[(size_t)(s + 7) * N]);
    }
  }
  const float ma = fminf(fminf(m0, m1), fminf(m2, m3));
  const float mb = fminf(fminf(m4, m5), fminf(m6, m7));
  float d = sqrtf(fmaxf(fminf(ma, mb), 0.0f));

  for (int off = 32; off > 0; off >>= 1) d += __shfl_down(d, off, 64);
  __shared__ float red[THREADS / 64];
  const int wave = threadIdx.x >> 6;
  const int lane = threadIdx.x & 63;
  if (lane == 0) red[wave] = d;
  __syncthreads();
  if (threadIdx.x == 0) {
    float s = 0.0f;
    for (int wv = 0; wv < THREADS / 64; ++wv) s += red[wv];
    atomicAdd(out, s);
  }
}

extern "C" void kernel_launch(void* const* d_in, const int* in_sizes, int n_in,
                              void* d_out, int out_size, void* d_ws, size_t ws_size,
                              hipStream_t stream) {
  const float* p1 = (const float*)d_in[0];
  const float* p2 = (const float*)d_in[1];
  float* out = (float*)d_out;
  float* ws = (float*)d_ws;

  // ws: rowPart[16][N] (1MB) + colW[512][N] (32MB). Harness re-poison fill
  // proves ws_size >= 256MB.
  float* rowPart = ws;
  float* colW = ws + (size_t)NCHUNKS * N;

  chamfer_mfma<<<dim3(NSTRIPS * NCHUNKS), THREADS, 0, stream>>>(
      p1, p2, rowPart, colW, out);
  chamfer_sum<<<dim3((2 * N) / THREADS), THREADS, 0, stream>>>(rowPart, colW,
                                                               out);
}

// Round 14
// 88.900 us; speedup vs baseline: 1.3004x; 1.3004x over previous
//
#include <hip/hip_runtime.h>
#include <math.h>

// Chamfer distance, N=M=16384, D=3, fp32 — R16 = R15 minus the broken
// inline-asm MFMA. R15's absmax=256 was an MFMA->VALU RAW hazard: CDNA does
// not interlock MFMA D-reg reads; the compiler schedules the required waits
// for the BUILTIN only. Asm MFMA dropped for good. Kept from R15 (all safe):
//  1. per-(wave,half) cbuf rows: each lane tree-mins its OWN 32 C values
//     (its half's rows across both tiles; halves partition the wave's 64
//     i's) -> 1 plain ds_write/iter. No shfl_xor in the loop (R12 had one:
//     ~120cy DS latency link), no global col traffic (R14's regression).
//  2. v_min3_f32 tree (safe simple-VALU asm, in use since R8).
//  3. b-fragment prefetch one iter ahead.
// Slot packing (bit-clean R9-R14): k0-8 2-way-split cross terms,
// k9-11 |a|^2 3-way (x1 on B), k12-14 |b|^2 3-way (x1 on A).

typedef short s16x8 __attribute__((ext_vector_type(8)));
typedef float f32x16 __attribute__((ext_vector_type(16)));

constexpr int N       = 16384;
constexpr int THREADS = 256;           // 4 waves
constexpr int ISTRIP  = 256;           // i's per block (4 waves x 2 tiles x 32)
constexpr int NSTRIPS = N / ISTRIP;    // 64
constexpr int JCHUNK  = 1024;          // j's per block
constexpr int NCHUNKS = N / JCHUNK;    // 16
constexpr int NJT     = JCHUNK / 32;   // 32 j-tiles
constexpr int CBW     = 1032;          // cbuf row stride (1024+8: 2-way banks)
constexpr float INF_F = 3.402823466e+38f;
constexpr short ONE_BF = (short)0x3F80;  // bf16(1.0)

static __device__ __forceinline__ short bf_hi(float x) {  // RN bf16 bits
  unsigned u = __float_as_uint(x);
  unsigned r = (u + 0x7fffu + ((u >> 16) & 1u)) >> 16;
  return (short)r;
}
static __device__ __forceinline__ float bf_val(short h) {
  return __uint_as_float(((unsigned)(unsigned short)h) << 16);
}
static __device__ __forceinline__ float min3f(float a, float b, float c) {
  float d;
  asm("v_min3_f32 %0, %1, %2, %3" : "=v"(d) : "v"(a), "v"(b), "v"(c));
  return d;
}

__global__ __launch_bounds__(THREADS, 2) void chamfer_mfma(
    const float* __restrict__ p1, const float* __restrict__ p2,
    float* __restrict__ rowPart, float* __restrict__ colPart,
    float* __restrict__ out) {
  // bfrag 32KB (rmt row-transpose aliases it after the post-loop barrier)
  // + cbuf [8 (w,half)][1032] 33KB = 64.25KB -> 2 blocks/CU (R13 showed
  // occupancy is not the binding constraint).
  __shared__ __align__(16) float smem[8192 + 8 * CBW];
  s16x8* const bfrag = (s16x8*)smem;
  float* const rmt   = smem;
  float* const cbuf  = smem + 8192;

  const int tid  = threadIdx.x;
  const int l    = tid & 63;
  const int w    = tid >> 6;
  const int cl   = l & 31;   // col-in-tile (B,C) / row-in-tile (A)
  const int half = l >> 5;   // k-octet owner / C row-quadrant owner
  const int bid  = blockIdx.x;
  const int strip = bid & (NSTRIPS - 1);
  const int chunk = bid >> 6;            // NSTRIPS == 64
  const int i0 = strip * ISTRIP;
  const int j0 = chunk * JCHUNK;

  if (bid == 0 && tid == 0) *out = 0.0f;  // ordered before sum's atomics

  // ---- stage B fragments: 4 points per thread ----
  for (int jl = tid; jl < JCHUNK; jl += THREADS) {
    const float* bp = p2 + (size_t)(j0 + jl) * 3;
    const float ox = bp[0], oy = bp[1], oz = bp[2];
    const float sb = fmaf(ox, ox, fmaf(oy, oy, oz * oz));
    const float bx = -2.0f * ox, by = -2.0f * oy, bz = -2.0f * oz;
    const short bhx = bf_hi(bx), blx = bf_hi(bx - bf_val(bhx));
    const short bhy = bf_hi(by), bly = bf_hi(by - bf_val(bhy));
    const short bhz = bf_hi(bz), blz = bf_hi(bz - bf_val(bhz));
    const short sbh = bf_hi(sb);
    const float r1 = sb - bf_val(sbh);
    const short sbm = bf_hi(r1);
    const short sbl = bf_hi(r1 - bf_val(sbm));
    const int jt = jl >> 5, c = jl & 31;
    bfrag[jt * 64 + c]      = (s16x8){bhx, blx, bhx, bhy, bly, bhy, bhz, blz};
    bfrag[jt * 64 + 32 + c] = (s16x8){bhz, ONE_BF, ONE_BF, ONE_BF,
                                      sbh, sbm, sbl, 0};
  }

  // ---- A fragments: 2 row-tiles (64 i's) per wave, in registers ----
#define ABUILD(t, AF)                                                        \
  s16x8 AF;                                                                  \
  {                                                                          \
    const float* ap = p1 + (size_t)(i0 + w * 64 + (t)*32 + cl) * 3;          \
    const float x = ap[0], y = ap[1], z = ap[2];                             \
    const float sa = fmaf(x, x, fmaf(y, y, z * z));                          \
    const short ahx = bf_hi(x), alx = bf_hi(x - bf_val(ahx));                \
    const short ahy = bf_hi(y), aly = bf_hi(y - bf_val(ahy));                \
    const short ahz = bf_hi(z), alz = bf_hi(z - bf_val(ahz));                \
    const short sah = bf_hi(sa);                                             \
    const float q1 = sa - bf_val(sah);                                       \
    const short sam = bf_hi(q1);                                             \
    const short sal = bf_hi(q1 - bf_val(sam));                               \
    AF = half ? (s16x8){alz, sah, sam, sal, ONE_BF, ONE_BF, ONE_BF, 0}       \
              : (s16x8){ahx, ahx, alx, ahy, ahy, aly, ahz, ahz};             \
  }
  ABUILD(0, A0) ABUILD(1, A1)
#undef ABUILD

  f32x16 RAa, RAb, zero16;
#pragma unroll
  for (int r = 0; r < 16; ++r) { RAa[r] = INF_F; RAb[r] = INF_F; zero16[r] = 0.0f; }

  __syncthreads();

  // jt-loop. Per iter: 1 ds_read_b128 (prefetched one ahead), 2 builtin
  // MFMA, 32 RA-min + 16 merge-min + 8 min3-tree, 1 plain ds_write. Zero
  // cross-lane ops, zero exec masks, zero barriers.
  float* const cwr = &cbuf[(w * 2 + half) * CBW + cl];
  s16x8 bfc = bfrag[l];  // jt = 0
#pragma unroll 2
  for (int jt = 0; jt < NJT; ++jt) {
    const s16x8 bfn = bfrag[(((jt + 1) & (NJT - 1)) << 6) + l];
    const f32x16 C0 =
        __builtin_amdgcn_mfma_f32_32x32x16_bf16(A0, bfc, zero16, 0, 0, 0);
    const f32x16 C1 =
        __builtin_amdgcn_mfma_f32_32x32x16_bf16(A1, bfc, zero16, 0, 0, 0);
    RAa = __builtin_elementwise_min(RAa, C0);
    RAb = __builtin_elementwise_min(RAb, C1);
    const f32x16 t = __builtin_elementwise_min(C0, C1);
    const float a0 = min3f(t[0], t[1], t[2]);
    const float a1 = min3f(t[3], t[4], t[5]);
    const float a2 = min3f(t[6], t[7], t[8]);
    const float a3 = min3f(t[9], t[10], t[11]);
    const float a4 = min3f(t[12], t[13], t[14]);
    const float b0 = min3f(a0, a1, t[15]);
    const float b1 = min3f(a2, a3, a4);
    cwr[jt * 32] = fminf(b0, b1);
    bfc = bfn;
  }

  __syncthreads();  // all bfrag reads + cbuf writes done

  // ---- row-min finish via LDS transpose (aliases bfrag; wave-local) ----
  {
    float* ra = &rmt[((w * 2 + 0) * 32 + cl) * 32 + half * 16];
    *(float4*)(ra + 0)  = make_float4(RAa[0], RAa[1], RAa[2], RAa[3]);
    *(float4*)(ra + 4)  = make_float4(RAa[4], RAa[5], RAa[6], RAa[7]);
    *(float4*)(ra + 8)  = make_float4(RAa[8], RAa[9], RAa[10], RAa[11]);
    *(float4*)(ra + 12) = make_float4(RAa[12], RAa[13], RAa[14], RAa[15]);
    float* rb = &rmt[((w * 2 + 1) * 32 + cl) * 32 + half * 16];
    *(float4*)(rb + 0)  = make_float4(RAb[0], RAb[1], RAb[2], RAb[3]);
    *(float4*)(rb + 4)  = make_float4(RAb[4], RAb[5], RAb[6], RAb[7]);
    *(float4*)(rb + 8)  = make_float4(RAb[8], RAb[9], RAb[10], RAb[11]);
    *(float4*)(rb + 12) = make_float4(RAb[12], RAb[13], RAb[14], RAb[15]);
  }
  {
    const int tl = l >> 5;
    const int s  = l & 31;
    const float* rp = &rmt[((w * 2 + tl) * 32) * 32 + s];
    float m = rp[0];
#pragma unroll
    for (int k = 1; k < 32; ++k) m = fminf(m, rp[k * 32]);
    const int r = s & 15, hh = s >> 4;
    const int row = (r & 3) + 8 * (r >> 2) + 4 * hh;
    rowPart[(size_t)chunk * N + i0 + w * 64 + tl * 32 + row] = m;
  }

  // ---- col-min finish: merge the 8 (wave,half) cbuf rows ----
  for (int c = tid; c < JCHUNK; c += THREADS) {
    float m = cbuf[c];
#pragma unroll
    for (int r = 1; r < 8; ++r) m = fminf(m, cbuf[r * CBW + c]);
    colPart[(size_t)strip * N + j0 + c] = m;
  }
}

// One thread per point (2*16384): min over partials (d^2 complete — norms
// were inside the MFMA), sqrt, block-sum, one atomicAdd into out[0].
__global__ __launch_bounds__(THREADS) void chamfer_sum(
    const float* __restrict__ rowPart, const float* __restrict__ colPart,
    float* __restrict__ out) {
  const int p = blockIdx.x * THREADS + threadIdx.x;  // 0..32767
  float m0 = INF_F, m1 = INF_F, m2 = INF_F, m3 = INF_F;
  if (p < N) {
    const float* rp = rowPart + p;
#pragma unroll
    for (int c = 0; c < NCHUNKS; c += 4) {
      m0 = fminf(m0, rp[(size_t)(c + 0) * N]);
      m1 = fminf(m1, rp[(size_t)(c + 1) * N]);
      m2 = fminf(m2, rp[(size_t)(c + 2) * N]);
      m3 = fminf(m3, rp[(size_t)(c + 3) * N]);
    }
  } else {
    const float* cp = colPart + (p - N);
    for (int s = 0; s < NSTRIPS; s += 4) {
      m0 = fminf(m0, cp[(size_t)(s + 0) * N]);
      m1 = fminf(m1, cp[(size_t)(s + 1) * N]);
      m2 = fminf(m2, cp[(size_t)(s + 2) * N]);
      m3 = fminf(m3, cp[(size_t)(s + 3) * N]);
    }
  }
  float d = sqrtf(fmaxf(fminf(fminf(m0, m1), fminf(m2, m3)), 0.0f));

  for (int off = 32; off > 0; off >>= 1) d += __shfl_down(d, off, 64);
  __shared__ float red[THREADS / 64];
  const int wave = threadIdx.x >> 6;
  const int lane = threadIdx.x & 63;
  if (lane == 0) red[wave] = d;
  __syncthreads();
  if (threadIdx.x == 0) {
    float s = 0.0f;
    for (int wv = 0; wv < THREADS / 64; ++wv) s += red[wv];
    atomicAdd(out, s);
  }
}

extern "C" void kernel_launch(void* const* d_in, const int* in_sizes, int n_in,
                              void* d_out, int out_size, void* d_ws, size_t ws_size,
                              hipStream_t stream) {
  const float* p1 = (const float*)d_in[0];
  const float* p2 = (const float*)d_in[1];
  float* out = (float*)d_out;
  float* ws = (float*)d_ws;

  // ws: rowPart[NCHUNKS=16][N] (1MB) + colPart[NSTRIPS=64][N] (4MB).
  float* rowPart = ws;
  float* colPart = ws + (size_t)NCHUNKS * N;

  chamfer_mfma<<<dim3(NSTRIPS * NCHUNKS), THREADS, 0, stream>>>(
      p1, p2, rowPart, colPart, out);
  chamfer_sum<<<dim3((2 * N) / THREADS), THREADS, 0, stream>>>(rowPart, colPart,
                                                               out);
}